// Round 10
// baseline (305.494 us; speedup 1.0000x reference)
//
#include <hip/hip_runtime.h>
#include <math.h>

typedef unsigned short ushort_t;
typedef __attribute__((ext_vector_type(8))) short bf16x8;
typedef __attribute__((ext_vector_type(4))) float f32x4;
typedef __attribute__((ext_vector_type(8))) unsigned short us8;

typedef __attribute__((address_space(1))) unsigned int gu32;
typedef __attribute__((address_space(3))) unsigned int lu32;

__device__ __forceinline__ void gload16(const void* g, void* l) {
    __builtin_amdgcn_global_load_lds((const gu32*)g, (lu32*)l, 16, 0, 0);
}

__device__ __forceinline__ unsigned short f2bf(float f) {
    unsigned u = __float_as_uint(f);
    unsigned r = ((u >> 16) & 1u) + 0x7fffu;
    return (unsigned short)((u + r) >> 16);
}

// ---------------- workspace layout (float offsets) ----------------
#define HB_OFF    0ULL          // hb  [64][64][64][64] bf16  (8,388,608 slots)
#define WT2_OFF   8388608ULL    // wt2 [81][64][64] bf16      (165,888 slots)
#define UTB_OFF   11765760ULL   // utb [6272][64][8] bf16     (1,605,632 slots)
#define V0_OFF    13381632ULL
#define V1_OFF    13391872ULL
#define PART_OFF  13402112ULL   // part  [784][160][64] f32    8,028,160
#define PART2_OFF 21430272ULL   // part2 [16][160][64] f32       163,840
#define WB2_OFF   21594112ULL   // Wb [6272][160][8] bf16     (4,014,080 slots) end ~102MB

// ---------------- fused pre-pass: conv1 (blocks 0..8191) + weight prep ----------------
__global__ __launch_bounds__(256) void pre_kernel(const float* __restrict__ x,
                                                  const float* __restrict__ w,
                                                  const float* __restrict__ bias,
                                                  const float* __restrict__ pw,
                                                  const float* __restrict__ W,
                                                  ushort_t* __restrict__ hb,
                                                  ushort_t* __restrict__ wt2,
                                                  ushort_t* __restrict__ Wb) {
    int bid = blockIdx.x;
    int tid = threadIdx.x;
    if (bid < 8192) {
        // conv1: 1->64ch, k5, pad2, +bias, relu -> NHWC bf16
        int t = (bid & 1023) * 256 + tid;           // 262144 (b,y,x)
        int cg = bid >> 10;                         // 0..7
        int xx = t & 63, yy = (t >> 6) & 63, b = t >> 12;
        const float* xb = x + (size_t)b * 4096;
        float xv[25];
        #pragma unroll
        for (int ky = 0; ky < 5; ++ky) {
            int iy = yy + ky - 2;
            #pragma unroll
            for (int kx = 0; kx < 5; ++kx) {
                int ix = xx + kx - 2;
                bool ok = (iy >= 0 && iy < 64 && ix >= 0 && ix < 64);
                xv[ky * 5 + kx] = ok ? xb[iy * 64 + ix] : 0.f;
            }
        }
        us8 o;
        #pragma unroll
        for (int cc = 0; cc < 8; ++cc) {
            int c = cg * 8 + cc;
            float acc = bias[c];
            const float* wc = w + c * 25;
            #pragma unroll
            for (int k = 0; k < 25; ++k) acc = fmaf(xv[k], wc[k], acc);
            o[cc] = f2bf(fmaxf(acc, 0.f));
        }
        *(us8*)&hb[(size_t)t * 64 + cg * 8] = o;
    } else if (bid < 8192 + 1296) {
        int t = (bid - 8192) * 256 + tid;           // 331776
        int ic = t & 63, c = (t >> 6) & 63, p = t >> 12;
        wt2[t] = f2bf(pw[(size_t)(c * 64 + ic) * 81 + p]);
    } else {
        int t = (bid - 8192 - 1296) * 256 + tid;    // 1,003,520 threads x 8 elems
        const float* src = W + (size_t)t * 8;
        us8 o;
        #pragma unroll
        for (int j = 0; j < 8; ++j) o[j] = f2bf(src[j]);
        *(us8*)&Wb[(size_t)t * 8] = o;
    }
}

// ---------------- conv2 implicit-GEMM MFMA: ring-3, ONE barrier, counted vmcnt ----------
__global__ __launch_bounds__(256) void conv2_mfma_kernel(const ushort_t* __restrict__ hb,
                                                         const ushort_t* __restrict__ wt2,
                                                         const float* __restrict__ pb,
                                                         ushort_t* __restrict__ utb) {
    __shared__ ushort_t As[3][4096];
    __shared__ ushort_t Bs[3][4096];

    int tid = threadIdx.x;
    int w = tid >> 6, lane = tid & 63;
    int m0 = blockIdx.x * 64;

    int srow = w * 16 + (lane >> 3);
    int srcchunk = (lane & 7) ^ ((lane >> 3) & 7);
    unsigned gbaseA[2];
    #pragma unroll
    for (int k = 0; k < 2; ++k) {
        int r = srow + k * 8;
        int m = m0 + r;
        int b = m / 784, pos = m % 784;
        int oy = pos / 28, ox = pos % 28;
        gbaseA[k] = ((unsigned)((b * 64 + 2 * oy) * 64 + 2 * ox)) * 64 + srcchunk * 8;
    }
    unsigned gbaseB[2] = { (unsigned)srow * 64 + srcchunk * 8,
                           (unsigned)(srow + 8) * 64 + srcchunk * 8 };

    int fr = lane & 15, fq = lane >> 4;
    int rlow = fr & 7;
    int c0 = (fq ^ rlow) * 8;
    int c1 = ((4 + fq) ^ rlow) * 8;
    int rowA = w * 16 + fr;
    int offA0 = rowA * 64 + c0, offA1 = rowA * 64 + c1;
    int offB0[4], offB1[4];
    #pragma unroll
    for (int jf = 0; jf < 4; ++jf) {
        int rowB = jf * 16 + fr;
        offB0[jf] = rowB * 64 + c0;
        offB1[jf] = rowB * 64 + c1;
    }

    f32x4 acc[4] = {};

    auto stage = [&](int p) {
        int slot = p % 3;
        int ky = p / 9, kx = p % 9;
        unsigned koff = (unsigned)(ky * 4096 + kx * 64);
        unsigned boff = (unsigned)p * 4096;
        gload16(hb + gbaseA[0] + koff, &As[slot][w * 1024]);
        gload16(hb + gbaseA[1] + koff, &As[slot][w * 1024 + 512]);
        gload16(wt2 + boff + gbaseB[0], &Bs[slot][w * 1024]);
        gload16(wt2 + boff + gbaseB[1], &Bs[slot][w * 1024 + 512]);
    };

    auto tap = [&](int p) {
        const ushort_t* A = As[p % 3];
        const ushort_t* B = Bs[p % 3];
        bf16x8 a0 = *(const bf16x8*)&A[offA0];
        bf16x8 a1 = *(const bf16x8*)&A[offA1];
        bf16x8 b0[4], b1[4];
        #pragma unroll
        for (int jf = 0; jf < 4; ++jf) {
            b0[jf] = *(const bf16x8*)&B[offB0[jf]];
            b1[jf] = *(const bf16x8*)&B[offB1[jf]];
        }
        #pragma unroll
        for (int jf = 0; jf < 4; ++jf)
            acc[jf] = __builtin_amdgcn_mfma_f32_16x16x32_bf16(a0, b0[jf], acc[jf], 0, 0, 0);
        #pragma unroll
        for (int jf = 0; jf < 4; ++jf)
            acc[jf] = __builtin_amdgcn_mfma_f32_16x16x32_bf16(a1, b1[jf], acc[jf], 0, 0, 0);
    };

    stage(0);

    for (int p = 0; p < 81; ++p) {
        if (p < 80) {
            stage(p + 1);                                      // prefetch stays in flight
            asm volatile("s_waitcnt vmcnt(4)" ::: "memory");   // wait tap p's loads ONLY
        } else {
            asm volatile("s_waitcnt vmcnt(0)" ::: "memory");
        }
        __builtin_amdgcn_s_barrier();
        __builtin_amdgcn_sched_barrier(0);                     // no ds_read hoist above barrier
        tap(p);
    }

    // ---- fused epilogue: +bias, capsule squash (8-lane shfl), write utb bf16 ----
    float bv[4];
    #pragma unroll
    for (int jf = 0; jf < 4; ++jf) bv[jf] = pb[jf * 16 + fr];

    #pragma unroll
    for (int reg = 0; reg < 4; ++reg) {
        int m = m0 + w * 16 + fq * 4 + reg;
        int bb = m / 784, pos = m % 784;
        #pragma unroll
        for (int jf = 0; jf < 4; ++jf) {
            float val = acc[jf][reg] + bv[jf];
            float v2 = val * val;
            v2 += __shfl_xor(v2, 1);
            v2 += __shfl_xor(v2, 2);
            v2 += __shfl_xor(v2, 4);                // msq over j=0..7 of caps group
            float mag = sqrtf(v2 + 1e-9f);
            float sc = v2 / (1.f + v2) / (mag + 1e-9f);
            int g = jf * 2 + (fr >> 3);
            int j = fr & 7;
            utb[(size_t)((g * 784 + pos) * 64 + bb) * 8 + j] = f2bf(val * sc);
        }
    }
}

#define RPB 8
// ---------------- routing iter 0: 4 routes packed per MFMA (c uniform) ----------------
__global__ __launch_bounds__(256) void routing_iter0_kernel(const ushort_t* __restrict__ Wb,
                                                            const ushort_t* __restrict__ utb,
                                                            float* __restrict__ part) {
    __shared__ ushort_t Wl[RPB * 1280];   // 20 KB  [route][oi][8]
    __shared__ ushort_t Ul[RPB * 512];    // 8 KB   [route][batch][8]
    int tid = threadIdx.x;
    int lane = tid & 63;
    int wid = tid >> 6;                   // batch-quad
    int fr = lane & 15, fq = lane >> 4;
    int n0 = blockIdx.x * RPB;

    {
        int w64 = wid * 64;
        const ushort_t* wsrc = Wb + (size_t)n0 * 1280;
        #pragma unroll
        for (int k = 0; k < 5; ++k)
            gload16(wsrc + (size_t)(k * 256 + tid) * 8, &Wl[(k * 256 + w64) * 8]);
        const ushort_t* usrc = utb + (size_t)n0 * 512;
        #pragma unroll
        for (int k = 0; k < 2; ++k)
            gload16(usrc + (size_t)(k * 256 + tid) * 8, &Ul[(k * 256 + w64) * 8]);
    }
    __syncthreads();

    f32x4 s4[10] = {};
    #pragma unroll
    for (int g = 0; g < 2; ++g) {
        int t = g * 4 + fq;               // this lane's route within the pack
        bf16x8 bfrag = *(const bf16x8*)&Ul[(t * 64 + wid * 16 + fr) * 8];
        #pragma unroll
        for (int o = 0; o < 10; ++o) {
            bf16x8 afrag = *(const bf16x8*)&Wl[(t * 160 + o * 16 + fr) * 8];
            s4[o] = __builtin_amdgcn_mfma_f32_16x16x32_bf16(afrag, bfrag, s4[o], 0, 0, 0);
        }
    }

    float* pp = part + (size_t)blockIdx.x * 10240;
    int b = wid * 16 + fr;
    #pragma unroll
    for (int o = 0; o < 10; ++o)
        #pragma unroll
        for (int r = 0; r < 4; ++r)
            pp[(o * 16 + fq * 4 + r) * 64 + b] = s4[o][r];
}

// ---------------- routing iters 1-2 (uh cached) ----------------
template<int ITER>
__global__ __launch_bounds__(256) void routing5_kernel(const ushort_t* __restrict__ Wb,
                                                       const ushort_t* __restrict__ utb,
                                                       const float* __restrict__ v0,
                                                       const float* __restrict__ v1,
                                                       float* __restrict__ part) {
    __shared__ ushort_t Wl[RPB * 1280];
    __shared__ ushort_t Ul[RPB * 512];
    int tid = threadIdx.x;
    int lane = tid & 63;
    int wid = tid >> 6;
    int fr = lane & 15, fq = lane >> 4;
    int n0 = blockIdx.x * RPB;
    int b = wid * 16 + fr;

    {
        int w64 = wid * 64;
        const ushort_t* wsrc = Wb + (size_t)n0 * 1280;
        #pragma unroll
        for (int k = 0; k < 5; ++k)
            gload16(wsrc + (size_t)(k * 256 + tid) * 8, &Wl[(k * 256 + w64) * 8]);
        const ushort_t* usrc = utb + (size_t)n0 * 512;
        #pragma unroll
        for (int k = 0; k < 2; ++k)
            gload16(usrc + (size_t)(k * 256 + tid) * 8, &Ul[(k * 256 + w64) * 8]);
    }

    float vsum[40];
    #pragma unroll
    for (int o = 0; o < 10; ++o) {
        f32x4 a = *(const f32x4*)&v0[b * 160 + o * 16 + fq * 4];
        if (ITER == 2) {
            f32x4 cc = *(const f32x4*)&v1[b * 160 + o * 16 + fq * 4];
            a = a + cc;
        }
        *(f32x4*)&vsum[o * 4] = a;
    }

    __syncthreads();

    float sacc[40];
    #pragma unroll
    for (int q = 0; q < 40; ++q) sacc[q] = 0.f;

    const bf16x8 zf = {};
    const f32x4 zc = {};

    #pragma unroll 1
    for (int t = 0; t < RPB; ++t) {
        bf16x8 bfrag = zf;
        if (fq == 0) bfrag = *(const bf16x8*)&Ul[(t * 64 + b) * 8];

        f32x4 uh[10];
        #pragma unroll
        for (int o = 0; o < 10; ++o) {
            bf16x8 afrag = zf;
            if (fq == 0) afrag = *(const bf16x8*)&Wl[(t * 160 + o * 16 + fr) * 8];
            uh[o] = __builtin_amdgcn_mfma_f32_16x16x32_bf16(afrag, bfrag, zc, 0, 0, 0);
        }

        float c10[10];
        {
            float l[10];
            #pragma unroll
            for (int o = 0; o < 10; ++o) {
                float lo = uh[o][0] * vsum[o * 4] + uh[o][1] * vsum[o * 4 + 1] +
                           uh[o][2] * vsum[o * 4 + 2] + uh[o][3] * vsum[o * 4 + 3];
                lo += __shfl_xor(lo, 16);
                lo += __shfl_xor(lo, 32);
                l[o] = lo;
            }
            float m = l[0];
            #pragma unroll
            for (int o = 1; o < 10; ++o) m = fmaxf(m, l[o]);
            float sum = 0.f;
            #pragma unroll
            for (int o = 0; o < 10; ++o) { c10[o] = __expf(l[o] - m); sum += c10[o]; }
            float inv = 1.f / sum;
            #pragma unroll
            for (int o = 0; o < 10; ++o) c10[o] *= inv;
        }

        #pragma unroll
        for (int o = 0; o < 10; ++o) {
            float co = c10[o];
            sacc[o * 4 + 0] = fmaf(co, uh[o][0], sacc[o * 4 + 0]);
            sacc[o * 4 + 1] = fmaf(co, uh[o][1], sacc[o * 4 + 1]);
            sacc[o * 4 + 2] = fmaf(co, uh[o][2], sacc[o * 4 + 2]);
            sacc[o * 4 + 3] = fmaf(co, uh[o][3], sacc[o * 4 + 3]);
        }
    }

    float* pp = part + (size_t)blockIdx.x * 10240;
    #pragma unroll
    for (int o = 0; o < 10; ++o)
        #pragma unroll
        for (int r = 0; r < 4; ++r)
            pp[(o * 16 + fq * 4 + r) * 64 + b] = sacc[o * 4 + r];
}

// ---------------- reduce stage 1: 784 -> 16 partials ----------------
__global__ __launch_bounds__(256) void reduce_part1_kernel(const float* __restrict__ part,
                                                           float* __restrict__ part2) {
    int idx = blockIdx.x * 256 + threadIdx.x;      // 0..10239
    int kc = blockIdx.y;                           // 0..15
    const float* p = part + (size_t)kc * 49 * 10240 + idx;
    float a0 = 0.f, a1 = 0.f, a2 = 0.f, a3 = 0.f;
    #pragma unroll
    for (int k = 0; k < 48; k += 4) {
        a0 += p[(size_t)(k + 0) * 10240];
        a1 += p[(size_t)(k + 1) * 10240];
        a2 += p[(size_t)(k + 2) * 10240];
        a3 += p[(size_t)(k + 3) * 10240];
    }
    part2[kc * 10240 + idx] = ((a0 + a1) + (a2 + a3)) + p[48ULL * 10240];
}

// ---------------- reduce stage 2 + squash -> v; grid (10,4) ----------------
__global__ __launch_bounds__(256) void reduce_squash_kernel(const float* __restrict__ part2,
                                                            float scale,
                                                            float* __restrict__ v) {
    __shared__ float sv[16][17];
    int tid = threadIdx.x;
    int o = blockIdx.x;
    int i = tid >> 4, bl = tid & 15;
    int b = blockIdx.y * 16 + bl;
    int idx = (o * 16 + i) * 64 + b;
    float a0 = 0.f, a1 = 0.f, a2 = 0.f, a3 = 0.f;
    #pragma unroll
    for (int k = 0; k < 16; k += 4) {
        a0 += part2[(k + 0) * 10240 + idx];
        a1 += part2[(k + 1) * 10240 + idx];
        a2 += part2[(k + 2) * 10240 + idx];
        a3 += part2[(k + 3) * 10240 + idx];
    }
    float s = ((a0 + a1) + (a2 + a3)) * scale;
    sv[i][bl] = s * s;
    __syncthreads();
    float msq = 0.f;
    #pragma unroll
    for (int ii = 0; ii < 16; ++ii) msq += sv[ii][bl];
    float mag = sqrtf(msq + 1e-9f);
    float sc = msq / (1.f + msq) / (mag + 1e-9f);
    v[b * 160 + o * 16 + i] = s * sc;
}

extern "C" void kernel_launch(void* const* d_in, const int* in_sizes, int n_in,
                              void* d_out, int out_size, void* d_ws, size_t ws_size,
                              hipStream_t stream) {
    const float* x  = (const float*)d_in[0];
    const float* w1 = (const float*)d_in[1];
    const float* b1 = (const float*)d_in[2];
    const float* pw = (const float*)d_in[3];
    const float* pb = (const float*)d_in[4];
    const float* W  = (const float*)d_in[5];
    float* out = (float*)d_out;
    float* ws  = (float*)d_ws;

    ushort_t* hb    = (ushort_t*)(ws + HB_OFF);
    ushort_t* wt2   = (ushort_t*)(ws + WT2_OFF);
    ushort_t* utb   = (ushort_t*)(ws + UTB_OFF);
    float*    v0    = ws + V0_OFF;
    float*    v1    = ws + V1_OFF;
    float*    part  = ws + PART_OFF;
    float*    part2 = ws + PART2_OFF;
    ushort_t* Wb    = (ushort_t*)(ws + WB2_OFF);

    pre_kernel<<<13408, 256, 0, stream>>>(x, w1, b1, pw, W, hb, wt2, Wb);
    conv2_mfma_kernel<<<784, 256, 0, stream>>>(hb, wt2, pb, utb);

    routing_iter0_kernel<<<784, 256, 0, stream>>>(Wb, utb, part);
    reduce_part1_kernel<<<dim3(40, 16), 256, 0, stream>>>(part, part2);
    reduce_squash_kernel<<<dim3(10, 4), 256, 0, stream>>>(part2, 0.1f, v0);

    routing5_kernel<1><<<784, 256, 0, stream>>>(Wb, utb, v0, nullptr, part);
    reduce_part1_kernel<<<dim3(40, 16), 256, 0, stream>>>(part, part2);
    reduce_squash_kernel<<<dim3(10, 4), 256, 0, stream>>>(part2, 1.f, v1);

    routing5_kernel<2><<<784, 256, 0, stream>>>(Wb, utb, v0, v1, part);
    reduce_part1_kernel<<<dim3(40, 16), 256, 0, stream>>>(part, part2);
    reduce_squash_kernel<<<dim3(10, 4), 256, 0, stream>>>(part2, 1.f, out);
}

// Round 12
// 275.261 us; speedup vs baseline: 1.1098x; 1.1098x over previous
//
#include <hip/hip_runtime.h>
#include <math.h>

typedef unsigned short ushort_t;
typedef __attribute__((ext_vector_type(8))) short bf16x8;
typedef __attribute__((ext_vector_type(4))) float f32x4;
typedef __attribute__((ext_vector_type(8))) unsigned short us8;

typedef __attribute__((address_space(1))) unsigned int gu32;
typedef __attribute__((address_space(3))) unsigned int lu32;

__device__ __forceinline__ void gload16(const void* g, void* l) {
    __builtin_amdgcn_global_load_lds((const gu32*)g, (lu32*)l, 16, 0, 0);
}

__device__ __forceinline__ unsigned short f2bf(float f) {
    unsigned u = __float_as_uint(f);
    unsigned r = ((u >> 16) & 1u) + 0x7fffu;
    return (unsigned short)((u + r) >> 16);
}

// ---------------- workspace layout (float offsets) ----------------
#define HB_OFF    0ULL          // hb  [64][64][64][64] bf16  (8,388,608 slots)
#define WT2_OFF   8388608ULL    // wt2 [81][64][64] bf16      (165,888 slots)
#define UTB_OFF   11765760ULL   // utb [6272][64][8] bf16     (1,605,632 slots)
#define V0_OFF    13381632ULL
#define V1_OFF    13391872ULL
#define PART_OFF  13402112ULL   // part  [392][160][64] f32    4,014,080
#define PART2_OFF 21430272ULL   // part2 [14][160][64] f32       143,360
#define WB2_OFF   21594112ULL   // Wb [6272][160][8] bf16     (4,014,080 slots) end ~102MB

// ---------------- fused pre-pass: conv1 (blocks 0..8191) + weight prep ----------------
__global__ __launch_bounds__(256) void pre_kernel(const float* __restrict__ x,
                                                  const float* __restrict__ w,
                                                  const float* __restrict__ bias,
                                                  const float* __restrict__ pw,
                                                  const float* __restrict__ W,
                                                  ushort_t* __restrict__ hb,
                                                  ushort_t* __restrict__ wt2,
                                                  ushort_t* __restrict__ Wb) {
    int bid = blockIdx.x;
    int tid = threadIdx.x;
    if (bid < 8192) {
        int t = (bid & 1023) * 256 + tid;           // 262144 (b,y,x)
        int cg = bid >> 10;                         // 0..7
        int xx = t & 63, yy = (t >> 6) & 63, b = t >> 12;
        const float* xb = x + (size_t)b * 4096;
        float xv[25];
        #pragma unroll
        for (int ky = 0; ky < 5; ++ky) {
            int iy = yy + ky - 2;
            #pragma unroll
            for (int kx = 0; kx < 5; ++kx) {
                int ix = xx + kx - 2;
                bool ok = (iy >= 0 && iy < 64 && ix >= 0 && ix < 64);
                xv[ky * 5 + kx] = ok ? xb[iy * 64 + ix] : 0.f;
            }
        }
        us8 o;
        #pragma unroll
        for (int cc = 0; cc < 8; ++cc) {
            int c = cg * 8 + cc;
            float acc = bias[c];
            const float* wc = w + c * 25;
            #pragma unroll
            for (int k = 0; k < 25; ++k) acc = fmaf(xv[k], wc[k], acc);
            o[cc] = f2bf(fmaxf(acc, 0.f));
        }
        *(us8*)&hb[(size_t)t * 64 + cg * 8] = o;
    } else if (bid < 8192 + 1296) {
        int t = (bid - 8192) * 256 + tid;           // 331776
        int ic = t & 63, c = (t >> 6) & 63, p = t >> 12;
        wt2[t] = f2bf(pw[(size_t)(c * 64 + ic) * 81 + p]);
    } else {
        int t = (bid - 8192 - 1296) * 256 + tid;    // 1,003,520 threads x 8 elems
        const float* src = W + (size_t)t * 8;
        us8 o;
        #pragma unroll
        for (int j = 0; j < 8; ++j) o[j] = f2bf(src[j]);
        *(us8*)&Wb[(size_t)t * 8] = o;
    }
}

// ---------------- conv2 implicit-GEMM MFMA (R9 known-good) + fused squash ----------------
__global__ __launch_bounds__(256) void conv2_mfma_kernel(const ushort_t* __restrict__ hb,
                                                         const ushort_t* __restrict__ wt2,
                                                         const float* __restrict__ pb,
                                                         ushort_t* __restrict__ utb) {
    __shared__ ushort_t As[2][4096];
    __shared__ ushort_t Bs[2][4096];

    int tid = threadIdx.x;
    int w = tid >> 6, lane = tid & 63;
    int m0 = blockIdx.x * 64;

    int srow = w * 16 + (lane >> 3);
    int srcchunk = (lane & 7) ^ ((lane >> 3) & 7);
    unsigned gbaseA[2];
    #pragma unroll
    for (int k = 0; k < 2; ++k) {
        int r = srow + k * 8;
        int m = m0 + r;
        int b = m / 784, pos = m % 784;
        int oy = pos / 28, ox = pos % 28;
        gbaseA[k] = ((unsigned)((b * 64 + 2 * oy) * 64 + 2 * ox)) * 64 + srcchunk * 8;
    }
    unsigned gbaseB[2] = { (unsigned)srow * 64 + srcchunk * 8,
                           (unsigned)(srow + 8) * 64 + srcchunk * 8 };

    int fr = lane & 15, fq = lane >> 4;
    int rlow = fr & 7;
    int c0 = (fq ^ rlow) * 8;
    int c1 = ((4 + fq) ^ rlow) * 8;
    int rowA = w * 16 + fr;
    int offA0 = rowA * 64 + c0, offA1 = rowA * 64 + c1;
    int offB0[4], offB1[4];
    #pragma unroll
    for (int jf = 0; jf < 4; ++jf) {
        int rowB = jf * 16 + fr;
        offB0[jf] = rowB * 64 + c0;
        offB1[jf] = rowB * 64 + c1;
    }

    f32x4 acc[4] = {};

    auto stage = [&](int p, int buf) {
        int ky = p / 9, kx = p % 9;
        unsigned koff = (unsigned)(ky * 4096 + kx * 64);
        unsigned boff = (unsigned)p * 4096;
        gload16(hb + gbaseA[0] + koff, &As[buf][w * 1024]);
        gload16(hb + gbaseA[1] + koff, &As[buf][w * 1024 + 512]);
        gload16(wt2 + boff + gbaseB[0], &Bs[buf][w * 1024]);
        gload16(wt2 + boff + gbaseB[1], &Bs[buf][w * 1024 + 512]);
    };

    stage(0, 0);
    __syncthreads();

    for (int p = 0; p < 81; ++p) {
        int cur = p & 1;
        if (p < 80) stage(p + 1, cur ^ 1);
        const ushort_t* A = As[cur];
        const ushort_t* B = Bs[cur];
        bf16x8 a0 = *(const bf16x8*)&A[offA0];
        bf16x8 a1 = *(const bf16x8*)&A[offA1];
        bf16x8 b0[4], b1[4];
        #pragma unroll
        for (int jf = 0; jf < 4; ++jf) {
            b0[jf] = *(const bf16x8*)&B[offB0[jf]];
            b1[jf] = *(const bf16x8*)&B[offB1[jf]];
        }
        #pragma unroll
        for (int jf = 0; jf < 4; ++jf)
            acc[jf] = __builtin_amdgcn_mfma_f32_16x16x32_bf16(a0, b0[jf], acc[jf], 0, 0, 0);
        #pragma unroll
        for (int jf = 0; jf < 4; ++jf)
            acc[jf] = __builtin_amdgcn_mfma_f32_16x16x32_bf16(a1, b1[jf], acc[jf], 0, 0, 0);
        __syncthreads();
    }

    // ---- fused epilogue: +bias, capsule squash (8-lane shfl), write utb bf16 ----
    float bv[4];
    #pragma unroll
    for (int jf = 0; jf < 4; ++jf) bv[jf] = pb[jf * 16 + fr];

    #pragma unroll
    for (int reg = 0; reg < 4; ++reg) {
        int m = m0 + w * 16 + fq * 4 + reg;
        int bb = m / 784, pos = m % 784;
        #pragma unroll
        for (int jf = 0; jf < 4; ++jf) {
            float val = acc[jf][reg] + bv[jf];
            float v2 = val * val;
            v2 += __shfl_xor(v2, 1);
            v2 += __shfl_xor(v2, 2);
            v2 += __shfl_xor(v2, 4);
            float mag = sqrtf(v2 + 1e-9f);
            float sc = v2 / (1.f + v2) / (mag + 1e-9f);
            int g = jf * 2 + (fr >> 3);
            int j = fr & 7;
            utb[(size_t)((g * 784 + pos) * 64 + bb) * 8 + j] = f2bf(val * sc);
        }
    }
}

#define RPB 16
// ---------------- routing iter 0: 4 routes packed per MFMA, RPB=16 ----------------
__global__ __launch_bounds__(256) void routing_iter0_kernel(const ushort_t* __restrict__ Wb,
                                                            const ushort_t* __restrict__ utb,
                                                            float* __restrict__ part) {
    __shared__ ushort_t Wl[RPB * 1280];   // 40 KB  [route][oi][8]
    __shared__ ushort_t Ul[RPB * 512];    // 16 KB  [route][batch][8]
    int tid = threadIdx.x;
    int lane = tid & 63;
    int wid = tid >> 6;                   // batch-quad
    int fr = lane & 15, fq = lane >> 4;
    int n0 = blockIdx.x * RPB;

    {
        int w64 = wid * 64;
        const ushort_t* wsrc = Wb + (size_t)n0 * 1280;
        #pragma unroll
        for (int k = 0; k < 10; ++k)
            gload16(wsrc + (size_t)(k * 256 + tid) * 8, &Wl[(k * 256 + w64) * 8]);
        const ushort_t* usrc = utb + (size_t)n0 * 512;
        #pragma unroll
        for (int k = 0; k < 4; ++k)
            gload16(usrc + (size_t)(k * 256 + tid) * 8, &Ul[(k * 256 + w64) * 8]);
    }
    __syncthreads();

    f32x4 s4[10] = {};
    #pragma unroll
    for (int g = 0; g < 4; ++g) {
        int t = g * 4 + fq;               // this lane's route within the pack
        bf16x8 bfrag = *(const bf16x8*)&Ul[(t * 64 + wid * 16 + fr) * 8];
        #pragma unroll
        for (int o = 0; o < 10; ++o) {
            bf16x8 afrag = *(const bf16x8*)&Wl[(t * 160 + o * 16 + fr) * 8];
            s4[o] = __builtin_amdgcn_mfma_f32_16x16x32_bf16(afrag, bfrag, s4[o], 0, 0, 0);
        }
    }

    float* pp = part + (size_t)blockIdx.x * 10240;
    int b = wid * 16 + fr;
    #pragma unroll
    for (int o = 0; o < 10; ++o)
        #pragma unroll
        for (int r = 0; r < 4; ++r)
            pp[(o * 16 + fq * 4 + r) * 64 + b] = s4[o][r];
}

// ---------------- routing iters 1-2 (uh cached), RPB=16 ----------------
template<int ITER>
__global__ __launch_bounds__(256) void routing5_kernel(const ushort_t* __restrict__ Wb,
                                                       const ushort_t* __restrict__ utb,
                                                       const float* __restrict__ v0,
                                                       const float* __restrict__ v1,
                                                       float* __restrict__ part) {
    __shared__ ushort_t Wl[RPB * 1280];
    __shared__ ushort_t Ul[RPB * 512];
    int tid = threadIdx.x;
    int lane = tid & 63;
    int wid = tid >> 6;
    int fr = lane & 15, fq = lane >> 4;
    int n0 = blockIdx.x * RPB;
    int b = wid * 16 + fr;

    {
        int w64 = wid * 64;
        const ushort_t* wsrc = Wb + (size_t)n0 * 1280;
        #pragma unroll
        for (int k = 0; k < 10; ++k)
            gload16(wsrc + (size_t)(k * 256 + tid) * 8, &Wl[(k * 256 + w64) * 8]);
        const ushort_t* usrc = utb + (size_t)n0 * 512;
        #pragma unroll
        for (int k = 0; k < 4; ++k)
            gload16(usrc + (size_t)(k * 256 + tid) * 8, &Ul[(k * 256 + w64) * 8]);
    }

    float vsum[40];
    #pragma unroll
    for (int o = 0; o < 10; ++o) {
        f32x4 a = *(const f32x4*)&v0[b * 160 + o * 16 + fq * 4];
        if (ITER == 2) {
            f32x4 cc = *(const f32x4*)&v1[b * 160 + o * 16 + fq * 4];
            a = a + cc;
        }
        *(f32x4*)&vsum[o * 4] = a;
    }

    __syncthreads();

    float sacc[40];
    #pragma unroll
    for (int q = 0; q < 40; ++q) sacc[q] = 0.f;

    const bf16x8 zf = {};
    const f32x4 zc = {};

    #pragma unroll 1
    for (int t = 0; t < RPB; ++t) {
        bf16x8 bfrag = zf;
        if (fq == 0) bfrag = *(const bf16x8*)&Ul[(t * 64 + b) * 8];

        f32x4 uh[10];
        #pragma unroll
        for (int o = 0; o < 10; ++o) {
            bf16x8 afrag = zf;
            if (fq == 0) afrag = *(const bf16x8*)&Wl[(t * 160 + o * 16 + fr) * 8];
            uh[o] = __builtin_amdgcn_mfma_f32_16x16x32_bf16(afrag, bfrag, zc, 0, 0, 0);
        }

        float c10[10];
        {
            float l[10];
            #pragma unroll
            for (int o = 0; o < 10; ++o) {
                float lo = uh[o][0] * vsum[o * 4] + uh[o][1] * vsum[o * 4 + 1] +
                           uh[o][2] * vsum[o * 4 + 2] + uh[o][3] * vsum[o * 4 + 3];
                lo += __shfl_xor(lo, 16);
                lo += __shfl_xor(lo, 32);
                l[o] = lo;
            }
            float m = l[0];
            #pragma unroll
            for (int o = 1; o < 10; ++o) m = fmaxf(m, l[o]);
            float sum = 0.f;
            #pragma unroll
            for (int o = 0; o < 10; ++o) { c10[o] = __expf(l[o] - m); sum += c10[o]; }
            float inv = 1.f / sum;
            #pragma unroll
            for (int o = 0; o < 10; ++o) c10[o] *= inv;
        }

        #pragma unroll
        for (int o = 0; o < 10; ++o) {
            float co = c10[o];
            sacc[o * 4 + 0] = fmaf(co, uh[o][0], sacc[o * 4 + 0]);
            sacc[o * 4 + 1] = fmaf(co, uh[o][1], sacc[o * 4 + 1]);
            sacc[o * 4 + 2] = fmaf(co, uh[o][2], sacc[o * 4 + 2]);
            sacc[o * 4 + 3] = fmaf(co, uh[o][3], sacc[o * 4 + 3]);
        }
    }

    float* pp = part + (size_t)blockIdx.x * 10240;
    #pragma unroll
    for (int o = 0; o < 10; ++o)
        #pragma unroll
        for (int r = 0; r < 4; ++r)
            pp[(o * 16 + fq * 4 + r) * 64 + b] = sacc[o * 4 + r];
}

// ---------------- reduce stage 1: 392 -> 14 partials; grid (40,14) ----------------
__global__ __launch_bounds__(256) void reduce_part1_kernel(const float* __restrict__ part,
                                                           float* __restrict__ part2) {
    int idx = blockIdx.x * 256 + threadIdx.x;      // 0..10239
    int kc = blockIdx.y;                           // 0..13
    const float* p = part + (size_t)kc * 28 * 10240 + idx;
    float a0 = 0.f, a1 = 0.f, a2 = 0.f, a3 = 0.f;
    #pragma unroll
    for (int k = 0; k < 28; k += 4) {
        a0 += p[(size_t)(k + 0) * 10240];
        a1 += p[(size_t)(k + 1) * 10240];
        a2 += p[(size_t)(k + 2) * 10240];
        a3 += p[(size_t)(k + 3) * 10240];
    }
    part2[kc * 10240 + idx] = (a0 + a1) + (a2 + a3);
}

// ---------------- reduce stage 2 + squash -> v; grid (10,4) ----------------
__global__ __launch_bounds__(256) void reduce_squash_kernel(const float* __restrict__ part2,
                                                            float scale,
                                                            float* __restrict__ v) {
    __shared__ float sv[16][17];
    int tid = threadIdx.x;
    int o = blockIdx.x;
    int i = tid >> 4, bl = tid & 15;
    int b = blockIdx.y * 16 + bl;
    int idx = (o * 16 + i) * 64 + b;
    float a0 = 0.f, a1 = 0.f, a2 = 0.f, a3 = 0.f;
    #pragma unroll
    for (int k = 0; k < 12; k += 4) {
        a0 += part2[(k + 0) * 10240 + idx];
        a1 += part2[(k + 1) * 10240 + idx];
        a2 += part2[(k + 2) * 10240 + idx];
        a3 += part2[(k + 3) * 10240 + idx];
    }
    a0 += part2[12 * 10240 + idx];
    a1 += part2[13 * 10240 + idx];
    float s = ((a0 + a1) + (a2 + a3)) * scale;
    sv[i][bl] = s * s;
    __syncthreads();
    float msq = 0.f;
    #pragma unroll
    for (int ii = 0; ii < 16; ++ii) msq += sv[ii][bl];
    float mag = sqrtf(msq + 1e-9f);
    float sc = msq / (1.f + msq) / (mag + 1e-9f);
    v[b * 160 + o * 16 + i] = s * sc;
}

extern "C" void kernel_launch(void* const* d_in, const int* in_sizes, int n_in,
                              void* d_out, int out_size, void* d_ws, size_t ws_size,
                              hipStream_t stream) {
    const float* x  = (const float*)d_in[0];
    const float* w1 = (const float*)d_in[1];
    const float* b1 = (const float*)d_in[2];
    const float* pw = (const float*)d_in[3];
    const float* pb = (const float*)d_in[4];
    const float* W  = (const float*)d_in[5];
    float* out = (float*)d_out;
    float* ws  = (float*)d_ws;

    ushort_t* hb    = (ushort_t*)(ws + HB_OFF);
    ushort_t* wt2   = (ushort_t*)(ws + WT2_OFF);
    ushort_t* utb   = (ushort_t*)(ws + UTB_OFF);
    float*    v0    = ws + V0_OFF;
    float*    v1    = ws + V1_OFF;
    float*    part  = ws + PART_OFF;
    float*    part2 = ws + PART2_OFF;
    ushort_t* Wb    = (ushort_t*)(ws + WB2_OFF);

    pre_kernel<<<13408, 256, 0, stream>>>(x, w1, b1, pw, W, hb, wt2, Wb);
    conv2_mfma_kernel<<<784, 256, 0, stream>>>(hb, wt2, pb, utb);

    routing_iter0_kernel<<<392, 256, 0, stream>>>(Wb, utb, part);
    reduce_part1_kernel<<<dim3(40, 14), 256, 0, stream>>>(part, part2);
    reduce_squash_kernel<<<dim3(10, 4), 256, 0, stream>>>(part2, 0.1f, v0);

    routing5_kernel<1><<<392, 256, 0, stream>>>(Wb, utb, v0, nullptr, part);
    reduce_part1_kernel<<<dim3(40, 14), 256, 0, stream>>>(part, part2);
    reduce_squash_kernel<<<dim3(10, 4), 256, 0, stream>>>(part2, 1.f, v1);

    routing5_kernel<2><<<392, 256, 0, stream>>>(Wb, utb, v0, v1, part);
    reduce_part1_kernel<<<dim3(40, 14), 256, 0, stream>>>(part, part2);
    reduce_squash_kernel<<<dim3(10, 4), 256, 0, stream>>>(part2, 1.f, out);
}